// Round 1
// baseline (156.445 us; speedup 1.0000x reference)
//
#include <hip/hip_runtime.h>
#include <cstddef>
#include <cstdint>

// 20 accumulators per batch:
//  0..3  : sum_i            (motor i)
//  4..7  : sumsq_i
//  8..13 : cross  (0,1),(0,2),(0,3),(1,2),(1,3),(2,3)   [corr_pairs order]
// 14..19 : absdiff(0,2),(1,3),(0,1),(1,2),(2,3),(3,0)   [diff_pairs order]
#define NACC 20
#define T_LEN 32768
#define NCH 24

__global__ __launch_bounds__(256) void cmfe_partial(const float* __restrict__ x,
                                                    float* __restrict__ ws,
                                                    int S) {
    const int blk = blockIdx.x;
    const int b   = blk / S;
    const int s   = blk - b * S;
    const int tchunk = T_LEN / S;
    const int t0  = s * tchunk;
    const float* xb = x + (size_t)b * NCH * T_LEN;

    float acc[NACC];
#pragma unroll
    for (int k = 0; k < NACC; ++k) acc[k] = 0.f;

    const int tid = threadIdx.x;
    const int nf4 = tchunk >> 2;   // float4 slots per channel slab

    for (int c = 0; c < 6; ++c) {
        const float4* p0 = reinterpret_cast<const float4*>(xb + (size_t)(c)      * T_LEN + t0);
        const float4* p1 = reinterpret_cast<const float4*>(xb + (size_t)(6 + c)  * T_LEN + t0);
        const float4* p2 = reinterpret_cast<const float4*>(xb + (size_t)(12 + c) * T_LEN + t0);
        const float4* p3 = reinterpret_cast<const float4*>(xb + (size_t)(18 + c) * T_LEN + t0);
        for (int i = tid; i < nf4; i += 256) {
            float4 a4 = p0[i];
            float4 b4 = p1[i];
            float4 c4 = p2[i];
            float4 d4 = p3[i];
            float av[4] = {a4.x, a4.y, a4.z, a4.w};
            float bv[4] = {b4.x, b4.y, b4.z, b4.w};
            float cv[4] = {c4.x, c4.y, c4.z, c4.w};
            float dv[4] = {d4.x, d4.y, d4.z, d4.w};
#pragma unroll
            for (int j = 0; j < 4; ++j) {
                const float A = av[j], B = bv[j], C = cv[j], D = dv[j];
                acc[0] += A; acc[1] += B; acc[2] += C; acc[3] += D;
                acc[4] = fmaf(A, A, acc[4]);
                acc[5] = fmaf(B, B, acc[5]);
                acc[6] = fmaf(C, C, acc[6]);
                acc[7] = fmaf(D, D, acc[7]);
                acc[8]  = fmaf(A, B, acc[8]);
                acc[9]  = fmaf(A, C, acc[9]);
                acc[10] = fmaf(A, D, acc[10]);
                acc[11] = fmaf(B, C, acc[11]);
                acc[12] = fmaf(B, D, acc[12]);
                acc[13] = fmaf(C, D, acc[13]);
                acc[14] += fabsf(A - C);
                acc[15] += fabsf(B - D);
                acc[16] += fabsf(A - B);
                acc[17] += fabsf(B - C);
                acc[18] += fabsf(C - D);
                acc[19] += fabsf(D - A);
            }
        }
    }

    // block reduce: wave64 shuffle tree, then LDS across the 4 waves
    __shared__ float lds[4][NACC];
    const int lane = tid & 63;
    const int wave = tid >> 6;
#pragma unroll
    for (int k = 0; k < NACC; ++k) {
        float v = acc[k];
        v += __shfl_down(v, 32, 64);
        v += __shfl_down(v, 16, 64);
        v += __shfl_down(v,  8, 64);
        v += __shfl_down(v,  4, 64);
        v += __shfl_down(v,  2, 64);
        v += __shfl_down(v,  1, 64);
        if (lane == 0) lds[wave][k] = v;
    }
    __syncthreads();
    if (tid < NACC) {
        float v = lds[0][tid] + lds[1][tid] + lds[2][tid] + lds[3][tid];
        ws[(size_t)blk * NACC + tid] = v;
    }
}

__global__ __launch_bounds__(64) void cmfe_finalize(const float* __restrict__ ws,
                                                    float* __restrict__ out,
                                                    int S, int B) {
    const int b = blockIdx.x * 64 + threadIdx.x;
    if (b >= B) return;

    float acc[NACC];
#pragma unroll
    for (int k = 0; k < NACC; ++k) acc[k] = 0.f;
    for (int s = 0; s < S; ++s) {
        const float* p = ws + ((size_t)b * S + s) * NACC;
#pragma unroll
        for (int k = 0; k < NACC; ++k) acc[k] += p[k];
    }

    const float N = 6.f * (float)T_LEN;   // 196608
    float sum[4], e[4];
#pragma unroll
    for (int i = 0; i < 4; ++i) { sum[i] = acc[i]; e[i] = acc[4 + i] / N; }

    const float mean = 0.25f * (e[0] + e[1] + e[2] + e[3]);
    float var = 0.f;
#pragma unroll
    for (int i = 0; i < 4; ++i) { float d = e[i] - mean; var += d * d; }
    const float estd = sqrtf(var * (1.f / 3.f));   // ddof=1

    const float emax = fmaxf(fmaxf(e[0], e[1]), fmaxf(e[2], e[3]));
    const float emin = fminf(fminf(e[0], e[1]), fminf(e[2], e[3]));
    const float ratio = emax / (emin + 1e-8f);

    float norm[4];
#pragma unroll
    for (int i = 0; i < 4; ++i) norm[i] = sqrtf(acc[4 + i] - sum[i] * sum[i] / N);

    const int pi[6] = {0, 0, 0, 1, 1, 2};
    const int pj[6] = {1, 2, 3, 2, 3, 3};
    float corr[6];
#pragma unroll
    for (int p = 0; p < 6; ++p) {
        const float G = acc[8 + p] - sum[pi[p]] * sum[pj[p]] / N;
        corr[p] = G / (norm[pi[p]] * norm[pj[p]] + 1e-8f);
    }

    float* o = out + (size_t)b * 14;
    o[0] = estd;
    o[1] = ratio;
#pragma unroll
    for (int p = 0; p < 6; ++p) o[2 + p] = corr[p];
#pragma unroll
    for (int p = 0; p < 6; ++p) o[8 + p] = acc[14 + p] / N;
}

extern "C" void kernel_launch(void* const* d_in, const int* in_sizes, int n_in,
                              void* d_out, int out_size, void* d_ws, size_t ws_size,
                              hipStream_t stream) {
    const float* x = (const float*)d_in[0];
    float* out = (float*)d_out;
    float* ws  = (float*)d_ws;

    const int B = in_sizes[0] / (NCH * T_LEN);   // 256

    int S = 16;                                   // t-chunks per batch
    while (S > 1 && (size_t)B * S * NACC * sizeof(float) > ws_size) S >>= 1;

    hipLaunchKernelGGL(cmfe_partial, dim3(B * S), dim3(256), 0, stream, x, ws, S);
    hipLaunchKernelGGL(cmfe_finalize, dim3((B + 63) / 64), dim3(64), 0, stream,
                       ws, out, S, B);
}

// Round 3
// 129.974 us; speedup vs baseline: 1.2037x; 1.2037x over previous
//
#include <hip/hip_runtime.h>
#include <cstddef>
#include <cstdint>

// 20 accumulators per batch:
//  0..3  : sum_i            (motor i)
//  4..7  : sumsq_i
//  8..13 : cross  (0,1),(0,2),(0,3),(1,2),(1,3),(2,3)   [corr_pairs order]
// 14..19 : absdiff(0,2),(1,3),(0,1),(1,2),(2,3),(3,0)   [diff_pairs order]
#define NACC 20
#define T_LEN 32768
#define NCH 24

typedef float f32x4 __attribute__((ext_vector_type(4)));

template <int S>
__global__ __launch_bounds__(256) void cmfe_partial(const float* __restrict__ x,
                                                    float* __restrict__ ws) {
    constexpr int tchunk = T_LEN / S;     // 1024 for S=32
    constexpr int nf4 = tchunk / 4;       // 256  for S=32
    const int blk = blockIdx.x;
    const int b   = blk / S;
    const int s   = blk - b * S;
    const int t0  = s * tchunk;
    const float* xb = x + (size_t)b * NCH * T_LEN + t0;

    float acc[NACC];
#pragma unroll
    for (int k = 0; k < NACC; ++k) acc[k] = 0.f;

    const int tid = threadIdx.x;

#pragma unroll
    for (int c = 0; c < 6; ++c) {
        const f32x4* p0 = reinterpret_cast<const f32x4*>(xb + (size_t)(c)      * T_LEN);
        const f32x4* p1 = reinterpret_cast<const f32x4*>(xb + (size_t)(6 + c)  * T_LEN);
        const f32x4* p2 = reinterpret_cast<const f32x4*>(xb + (size_t)(12 + c) * T_LEN);
        const f32x4* p3 = reinterpret_cast<const f32x4*>(xb + (size_t)(18 + c) * T_LEN);
#pragma unroll
        for (int i0 = 0; i0 < nf4; i0 += 256) {
            const int i = i0 + tid;
            f32x4 a4 = __builtin_nontemporal_load(p0 + i);
            f32x4 b4 = __builtin_nontemporal_load(p1 + i);
            f32x4 c4 = __builtin_nontemporal_load(p2 + i);
            f32x4 d4 = __builtin_nontemporal_load(p3 + i);
#pragma unroll
            for (int j = 0; j < 4; ++j) {
                const float A = a4[j], B = b4[j], C = c4[j], D = d4[j];
                acc[0] += A; acc[1] += B; acc[2] += C; acc[3] += D;
                acc[4] = fmaf(A, A, acc[4]);
                acc[5] = fmaf(B, B, acc[5]);
                acc[6] = fmaf(C, C, acc[6]);
                acc[7] = fmaf(D, D, acc[7]);
                acc[8]  = fmaf(A, B, acc[8]);
                acc[9]  = fmaf(A, C, acc[9]);
                acc[10] = fmaf(A, D, acc[10]);
                acc[11] = fmaf(B, C, acc[11]);
                acc[12] = fmaf(B, D, acc[12]);
                acc[13] = fmaf(C, D, acc[13]);
                acc[14] += fabsf(A - C);
                acc[15] += fabsf(B - D);
                acc[16] += fabsf(A - B);
                acc[17] += fabsf(B - C);
                acc[18] += fabsf(C - D);
                acc[19] += fabsf(D - A);
            }
        }
    }

    // block reduce: wave64 shuffle tree, then LDS across the 4 waves
    __shared__ float lds[4][NACC];
    const int lane = tid & 63;
    const int wave = tid >> 6;
#pragma unroll
    for (int k = 0; k < NACC; ++k) {
        float v = acc[k];
        v += __shfl_down(v, 32, 64);
        v += __shfl_down(v, 16, 64);
        v += __shfl_down(v,  8, 64);
        v += __shfl_down(v,  4, 64);
        v += __shfl_down(v,  2, 64);
        v += __shfl_down(v,  1, 64);
        if (lane == 0) lds[wave][k] = v;
    }
    __syncthreads();
    if (tid < NACC) {
        float v = lds[0][tid] + lds[1][tid] + lds[2][tid] + lds[3][tid];
        ws[(size_t)blk * NACC + tid] = v;
    }
}

template <int S>
__global__ __launch_bounds__(64) void cmfe_finalize(const float* __restrict__ ws,
                                                    float* __restrict__ out) {
    const int b = blockIdx.x;          // one block per batch
    const int tid = threadIdx.x;

    // lanes 0..19 each own one accumulator slot; sum the S partials
    __shared__ float accs[NACC];
    if (tid < NACC) {
        float v = 0.f;
        const float* p = ws + (size_t)b * S * NACC + tid;
#pragma unroll
        for (int s = 0; s < S; ++s) v += p[(size_t)s * NACC];
        accs[tid] = v;
    }
    __syncthreads();
    if (tid != 0) return;

    float acc[NACC];
#pragma unroll
    for (int k = 0; k < NACC; ++k) acc[k] = accs[k];

    const float N = 6.f * (float)T_LEN;   // 196608
    float sum[4], e[4];
#pragma unroll
    for (int i = 0; i < 4; ++i) { sum[i] = acc[i]; e[i] = acc[4 + i] / N; }

    const float mean = 0.25f * (e[0] + e[1] + e[2] + e[3]);
    float var = 0.f;
#pragma unroll
    for (int i = 0; i < 4; ++i) { float d = e[i] - mean; var += d * d; }
    const float estd = sqrtf(var * (1.f / 3.f));   // ddof=1

    const float emax = fmaxf(fmaxf(e[0], e[1]), fmaxf(e[2], e[3]));
    const float emin = fminf(fminf(e[0], e[1]), fminf(e[2], e[3]));
    const float ratio = emax / (emin + 1e-8f);

    float norm[4];
#pragma unroll
    for (int i = 0; i < 4; ++i) norm[i] = sqrtf(acc[4 + i] - sum[i] * sum[i] / N);

    const int pi[6] = {0, 0, 0, 1, 1, 2};
    const int pj[6] = {1, 2, 3, 2, 3, 3};
    float corr[6];
#pragma unroll
    for (int p = 0; p < 6; ++p) {
        const float G = acc[8 + p] - sum[pi[p]] * sum[pj[p]] / N;
        corr[p] = G / (norm[pi[p]] * norm[pj[p]] + 1e-8f);
    }

    float* o = out + (size_t)b * 14;
    o[0] = estd;
    o[1] = ratio;
#pragma unroll
    for (int p = 0; p < 6; ++p) o[2 + p] = corr[p];
#pragma unroll
    for (int p = 0; p < 6; ++p) o[8 + p] = acc[14 + p] / N;
}

extern "C" void kernel_launch(void* const* d_in, const int* in_sizes, int n_in,
                              void* d_out, int out_size, void* d_ws, size_t ws_size,
                              hipStream_t stream) {
    const float* x = (const float*)d_in[0];
    float* out = (float*)d_out;
    float* ws  = (float*)d_ws;

    const int B = in_sizes[0] / (NCH * T_LEN);   // 256

    if ((size_t)B * 32 * NACC * sizeof(float) <= ws_size) {
        constexpr int S = 32;
        hipLaunchKernelGGL(cmfe_partial<S>, dim3(B * S), dim3(256), 0, stream, x, ws);
        hipLaunchKernelGGL(cmfe_finalize<S>, dim3(B), dim3(64), 0, stream, ws, out);
    } else {
        constexpr int S = 8;
        hipLaunchKernelGGL(cmfe_partial<S>, dim3(B * S), dim3(256), 0, stream, x, ws);
        hipLaunchKernelGGL(cmfe_finalize<S>, dim3(B), dim3(64), 0, stream, ws, out);
    }
}